// Round 13
// baseline (87.536 us; speedup 1.0000x reference)
//
#include <hip/hip_runtime.h>

#define N_NODES 50000
#define N_EDGES 800000
#define N_RELS  8
#define NCOL    576          // 9 * 64 output cols (8 relations + self-loop)
#define MAXDEG  64
#define BPACK_ELEMS (NCOL * 64)                          // 36864 bf16
#define NTILE   (N_NODES / 16)     // 3125 hw tiles

// bucketing: 64 nodes per bucket, bucket = dst >> 6
#define NBUK    782                // 782*64 = 50048 >= 50000
#define BUKCAP  1280               // lambda=1023, sigma~32 -> +8 sigma
#define ABLK    256                // blocks that also run the bin phase
#define ACHUNK  3125               // 256 * 3125 = 800000 exactly

typedef __attribute__((ext_vector_type(8))) short short8;
typedef __attribute__((ext_vector_type(4))) float f32x4;

static __device__ __forceinline__ short f2bf(float f) {
    unsigned u = __float_as_uint(f);
    unsigned r = (u + 0x7FFFu + ((u >> 16) & 1u)) >> 16;   // RNE
    return (short)r;
}
static __device__ __forceinline__ float bf2f(unsigned short b) {
    return __uint_as_float(((unsigned)b) << 16);
}

// ---------------------------------------------------------------------------
// Pre-pack B (8 rels + self-loop) into MFMA fragment order; also zeroes gcnt.
// ---------------------------------------------------------------------------
__global__ __launch_bounds__(256) void k_bpack(const float* __restrict__ W,
                                               const float* __restrict__ lw,
                                               unsigned short* __restrict__ Bpack,
                                               int* __restrict__ gcnt) {
    const int id = blockIdx.x * 256 + threadIdx.x;
    if (id < NBUK) gcnt[id] = 0;
    if (id >= BPACK_ELEMS) return;
    const int e    = id & 7;
    const int lane = (id >> 3) & 63;
    const int g    = id >> 9;            // 0..71
    const int w    = g / 18;
    const int r18  = g - w * 18;
    const int t    = r18 >> 1;
    const int s    = r18 & 1;
    const int c0   = w * 144 + t * 16;
    const int rel  = c0 >> 6;
    const int cc   = (c0 & 63) + (lane & 15);
    const int kk   = s * 32 + (lane >> 4) * 8 + e;
    const float* Bp = (rel < 8) ? (W + (size_t)rel * 4096) : lw;
    Bpack[id] = (unsigned short)f2bf(Bp[(size_t)kk * 64 + cc]);
}

// ---------------------------------------------------------------------------
// MERGED: MFMA transform (all 3125 blocks) + bucket-bin (blocks 0..255).
// Bin phase (round-12-proven): LDS count -> one global atomic per
// (block,bucket) reserving a contiguous run -> place ~32B runs in bedges.
// LDS is a union: hw staging tile first, bin counters after (barrier-split).
// Copy-out vectorized to uint4 (swizzle commutes: XOR only touches u32-index
// bits >=3, so in dwordx4 units it is j ^ ((row>>2)<<1)).
// ---------------------------------------------------------------------------
__global__ __launch_bounds__(256) void k_hwabin(const float* __restrict__ h,
                                                const unsigned short* __restrict__ Bpack,
                                                unsigned short* __restrict__ hw2,
                                                const int* __restrict__ src,
                                                const int* __restrict__ dst,
                                                const int* __restrict__ rel,
                                                const float* __restrict__ norm,
                                                int* __restrict__ gcnt,
                                                int2* __restrict__ bedges) {
    __shared__ union U {
        unsigned short hwl[16 * NCOL];                       // 18432 B
        struct { int lcnt[NBUK]; int lbase[NBUK]; int lpos[NBUK]; } a;  // 9384 B
    } u;

    const int lane  = threadIdx.x & 63;
    const int w     = threadIdx.x >> 6;
    const int l15   = lane & 15;
    const int lg    = lane >> 4;           // 0..3
    const int wcol0 = w * 144;
    const int n0    = blockIdx.x * 16;

    short8 barr[9][2];
#pragma unroll
    for (int t = 0; t < 9; ++t)
#pragma unroll
        for (int s = 0; s < 2; ++s)
            barr[t][s] = *(const short8*)(Bpack + ((size_t)(w * 18 + t * 2 + s) * 64 + lane) * 8);

    short8 afr[2];
    const float* hp = h + (size_t)(n0 + l15) * 64 + lg * 8;
#pragma unroll
    for (int s = 0; s < 2; ++s) {
        const float4 x = *(const float4*)(hp + s * 32);
        const float4 y = *(const float4*)(hp + s * 32 + 4);
        short8 a;
        a[0] = f2bf(x.x); a[1] = f2bf(x.y); a[2] = f2bf(x.z); a[3] = f2bf(x.w);
        a[4] = f2bf(y.x); a[5] = f2bf(y.y); a[6] = f2bf(y.z); a[7] = f2bf(y.w);
        afr[s] = a;
    }

    f32x4 acc[9];
#pragma unroll
    for (int t = 0; t < 9; ++t) {
        f32x4 c = {0.f, 0.f, 0.f, 0.f};
        c = __builtin_amdgcn_mfma_f32_16x16x32_bf16(afr[0], barr[t][0], c, 0, 0, 0);
        c = __builtin_amdgcn_mfma_f32_16x16x32_bf16(afr[1], barr[t][1], c, 0, 0, 0);
        acc[t] = c;
    }

    // stage D through swizzled LDS: (row,c) -> u16 idx row*576 + (c ^ (lg<<4))
#pragma unroll
    for (int t = 0; t < 9; ++t) {
        const int c = wcol0 + t * 16 + l15;
#pragma unroll
        for (int r = 0; r < 4; ++r) {
            const int row = lg * 4 + r;   // D: col=lane&15, row=lg*4+reg
            u.hwl[row * NCOL + (c ^ (lg << 4))] = (unsigned short)f2bf(acc[t][r]);
        }
    }
    __syncthreads();

    // vectorized copy-out: 16 rows x 72 uint4 (1152 total, 4.5/thread)
    const uint4* ldsv = (const uint4*)u.hwl;   // row pitch 72 uint4
    uint4* outv = (uint4*)hw2;
    for (int i = threadIdx.x; i < 16 * 72; i += 256) {
        const int row = i / 72;
        const int j   = i - row * 72;
        outv[(size_t)(n0 + row) * 72 + j] = ldsv[row * 72 + (j ^ ((row >> 2) << 1))];
    }

    // ---- bin phase: first ABLK blocks only (they dispatch first)
    if (blockIdx.x < ABLK) {
        __syncthreads();   // copy-out LDS reads done before union reuse
        for (int i = threadIdx.x; i < NBUK; i += 256) { u.a.lcnt[i] = 0; u.a.lpos[i] = 0; }
        __syncthreads();

        const int e0 = blockIdx.x * ACHUNK;
        for (int e = e0 + threadIdx.x; e < e0 + ACHUNK; e += 256)
            atomicAdd(&u.a.lcnt[dst[e] >> 6], 1);
        __syncthreads();

        for (int i = threadIdx.x; i < NBUK; i += 256)
            u.a.lbase[i] = atomicAdd(&gcnt[i], u.a.lcnt[i]);
        __syncthreads();

        for (int e = e0 + threadIdx.x; e < e0 + ACHUNK; e += 256) {
            const int dv  = dst[e];
            const int bkt = dv >> 6;
            int idx = u.a.lbase[bkt] + atomicAdd(&u.a.lpos[bkt], 1);
            idx = min(idx, BUKCAP - 1);                   // OOB guard (~1e-15)
            bedges[(size_t)bkt * BUKCAP + idx] =
                make_int2(((dv & 63) << 19) | (src[e] * 9 + rel[e]),
                          __float_as_int(norm[e]));
        }
    }
}

// ---------------------------------------------------------------------------
// MERGED: bucket-sort into a 32KB LDS slot array + gather + epilogue.
// One block (512 thr = 8 waves) per bucket. Deletes the global payload array
// (-25.6MB write, -25.6MB read) and the k_bsort launch. Gather inner loop is
// the proven 8-deep-ILP structure (k_gather, 12us), 8 nodes per wave.
// ---------------------------------------------------------------------------
__global__ __launch_bounds__(512) void k_bgather(const unsigned short* __restrict__ hw2,
                                                 const int2* __restrict__ bedges,
                                                 const int* __restrict__ gcnt,
                                                 const float* __restrict__ bias,
                                                 float* __restrict__ out) {
    __shared__ int2 pl[64][MAXDEG];   // 32 KB
    __shared__ int  lc[64];
    if (threadIdx.x < 64) lc[threadIdx.x] = 0;
    __syncthreads();

    const int b  = blockIdx.x;
    const int nb = min(gcnt[b], BUKCAP);
    const int2* be = bedges + (size_t)b * BUKCAP;

    for (int i = threadIdx.x; i < nb; i += 512) {
        const int2 r = be[i];
        const int  d = (unsigned)r.x >> 19;
        const int  pos = atomicAdd(&lc[d], 1) & (MAXDEG - 1);
        pl[d][pos] = make_int2(r.x & 0x7FFFF, r.y);
    }
    __syncthreads();

    const int lane = threadIdx.x & 63;
    const int wv   = threadIdx.x >> 6;     // 0..7
    const float bv = bias[lane];

    for (int rl = wv; rl < 64; rl += 8) {
        const int n = b * 64 + rl;
        if (n >= N_NODES) break;
        const int deg = min(lc[rl], MAXDEG);
        const int2* p = pl[rl];

        float a0 = bv + bf2f(hw2[(size_t)n * NCOL + 512 + lane]);  // self-loop
        float a1 = 0.f, a2 = 0.f, a3 = 0.f;
        int t = 0;
        for (; t + 8 <= deg; t += 8) {
            const int2 p0 = p[t],     p1 = p[t + 1], p2 = p[t + 2], p3 = p[t + 3];
            const int2 p4 = p[t + 4], p5 = p[t + 5], p6 = p[t + 6], p7 = p[t + 7];
            const float v0 = bf2f(hw2[(size_t)p0.x * 64 + lane]);
            const float v1 = bf2f(hw2[(size_t)p1.x * 64 + lane]);
            const float v2 = bf2f(hw2[(size_t)p2.x * 64 + lane]);
            const float v3 = bf2f(hw2[(size_t)p3.x * 64 + lane]);
            const float v4 = bf2f(hw2[(size_t)p4.x * 64 + lane]);
            const float v5 = bf2f(hw2[(size_t)p5.x * 64 + lane]);
            const float v6 = bf2f(hw2[(size_t)p6.x * 64 + lane]);
            const float v7 = bf2f(hw2[(size_t)p7.x * 64 + lane]);
            a0 += v0 * __int_as_float(p0.y);
            a1 += v1 * __int_as_float(p1.y);
            a2 += v2 * __int_as_float(p2.y);
            a3 += v3 * __int_as_float(p3.y);
            a0 += v4 * __int_as_float(p4.y);
            a1 += v5 * __int_as_float(p5.y);
            a2 += v6 * __int_as_float(p6.y);
            a3 += v7 * __int_as_float(p7.y);
        }
        for (; t < deg; ++t) {
            const int2 q = p[t];
            a0 += bf2f(hw2[(size_t)q.x * 64 + lane]) * __int_as_float(q.y);
        }
        out[(size_t)n * 64 + lane] = fmaxf((a0 + a1) + (a2 + a3), 0.f);
    }
}

// ---------------------------------------------------------------------------
// Fallback path (ws too small): per-edge direct matvec + f32 atomics + finish.
// ---------------------------------------------------------------------------
__global__ __launch_bounds__(256) void k_edge_direct(const float* __restrict__ h,
                                                     const float* __restrict__ W,
                                                     const int* __restrict__ src,
                                                     const int* __restrict__ dst,
                                                     const int* __restrict__ rel,
                                                     const float* __restrict__ norm,
                                                     float* __restrict__ agg) {
    const int lane  = threadIdx.x & 63;
    const int warp  = (blockIdx.x * 256 + threadIdx.x) >> 6;
    const int nwarp = (gridDim.x * 256) >> 6;
    for (int e = warp; e < N_EDGES; e += nwarp) {
        const int   s  = src[e];
        const int   d2 = dst[e];
        const int   rr = rel[e];
        const float nm = norm[e];
        const float4* hp = (const float4*)(h + (size_t)s * 64);
        const float*  Wr = W + (size_t)rr * 4096;
        float acc = 0.f;
#pragma unroll
        for (int q = 0; q < 16; ++q) {
            float4 hv = hp[q];
            acc += hv.x * Wr[(4 * q + 0) * 64 + lane];
            acc += hv.y * Wr[(4 * q + 1) * 64 + lane];
            acc += hv.z * Wr[(4 * q + 2) * 64 + lane];
            acc += hv.w * Wr[(4 * q + 3) * 64 + lane];
        }
        atomicAdd(&agg[(size_t)d2 * 64 + lane], acc * nm);
    }
}

__global__ __launch_bounds__(256) void k_final(float* __restrict__ out,
                                               const float* __restrict__ h,
                                               const float* __restrict__ lw,
                                               const float* __restrict__ bias) {
    __shared__ float lws[4096];
    for (int i = threadIdx.x; i < 4096; i += 256) lws[i] = lw[i];
    __syncthreads();
    const int lane  = threadIdx.x & 63;
    const int warp  = (blockIdx.x * 256 + threadIdx.x) >> 6;
    const int nwarp = (gridDim.x * 256) >> 6;
    const float b = bias[lane];
    for (int n = warp; n < N_NODES; n += nwarp) {
        const float4* hp = (const float4*)(h + (size_t)n * 64);
        float acc = b;
#pragma unroll
        for (int q = 0; q < 16; ++q) {
            float4 hv = hp[q];
            acc += hv.x * lws[(4 * q + 0) * 64 + lane];
            acc += hv.y * lws[(4 * q + 1) * 64 + lane];
            acc += hv.z * lws[(4 * q + 2) * 64 + lane];
            acc += hv.w * lws[(4 * q + 3) * 64 + lane];
        }
        const size_t idx = (size_t)n * 64 + lane;
        const float v = out[idx] + acc;
        out[idx] = v > 0.f ? v : 0.f;
    }
}

extern "C" void kernel_launch(void* const* d_in, const int* in_sizes, int n_in,
                              void* d_out, int out_size, void* d_ws, size_t ws_size,
                              hipStream_t stream) {
    const float* h    = (const float*)d_in[0];
    const float* norm = (const float*)d_in[1];
    const float* W    = (const float*)d_in[2];
    const float* lw   = (const float*)d_in[3];
    const float* bias = (const float*)d_in[4];
    const int*   src  = (const int*)d_in[5];
    const int*   dst  = (const int*)d_in[6];
    const int*   rel  = (const int*)d_in[7];
    float* out = (float*)d_out;

    // --- workspace layout -------------------------------------------------
    char* ws = (char*)d_ws;
    unsigned short* hw2 = (unsigned short*)ws;                  // 57.6 MB
    int2* bedges  = (int2*)(ws + (size_t)N_NODES * NCOL * 2);   // 782*1280*8 = 8.0 MB
    int*  gcnt    = (int*)(bedges + (size_t)NBUK * BUKCAP);     // 782
    unsigned short* Bpack = (unsigned short*)(gcnt + NBUK + 16);
    const size_t need = (size_t)((char*)(Bpack + BPACK_ELEMS) - ws);

    if (ws_size >= need) {
        k_bpack<<<196, 256, 0, stream>>>(W, lw, Bpack, gcnt);
        k_hwabin<<<NTILE, 256, 0, stream>>>(h, Bpack, hw2, src, dst, rel, norm,
                                            gcnt, bedges);
        k_bgather<<<NBUK, 512, 0, stream>>>(hw2, bedges, gcnt, bias, out);
    } else {
        // fallback: atomic scatter path
        hipMemsetAsync(out, 0, (size_t)out_size * sizeof(float), stream);
        k_edge_direct<<<2048, 256, 0, stream>>>(h, W, src, dst, rel, norm, out);
        k_final<<<1024, 256, 0, stream>>>(out, h, lw, bias);
    }
}